// Round 18
// baseline (236.549 us; speedup 1.0000x reference)
//
#include <hip/hip_runtime.h>
#include <math.h>

#define N_NODES 50000
#define N_EDGES 600000
#define DIM 128
#define NCLS 10
#define MTILES 391                       // ceil(50000/128)
#define CHUNKS_PER_TILE 2048             // 32 slots * 64 lanes, 8 fp16 each
#define NB_SCAN 49                       // ceil(50000/1024)

typedef _Float16 h2 __attribute__((ext_vector_type(2)));
typedef _Float16 half8 __attribute__((ext_vector_type(8)));
typedef __attribute__((ext_vector_type(4))) float f32x4;
typedef unsigned char uchar;

__device__ inline h2 pkh(float a, float b) {        // 2xf32 -> packed fp16 (RTZ)
    auto r = __builtin_amdgcn_cvt_pkrtz(a, b);
    return *(h2*)&r;
}
__device__ inline unsigned h2u(h2 v) { return *(unsigned*)&v; }
__device__ inline h2 u2h(unsigned u) { return *(h2*)&u; }

__device__ inline float dot2acc(h2 a, h2 b, float c) {
#if __has_builtin(__builtin_amdgcn_fdot2)
    return __builtin_amdgcn_fdot2(a, b, c, false);   // v_dot2_f32_f16
#else
    return fmaf((float)a.x, (float)b.x, fmaf((float)a.y, (float)b.y, c));
#endif
}

// e5m2 decode: byte is the TOP byte of an f16; one v_perm_b32 per h2 pair.
__device__ inline h2 dec2lo(unsigned w) {   // bytes 0,1 -> h2
    return u2h(__builtin_amdgcn_perm(0u, w, 0x010C000Cu));
}
__device__ inline h2 dec2hi(unsigned w) {   // bytes 2,3 -> h2
    return u2h(__builtin_amdgcn_perm(0u, w, 0x030C020Cu));
}
// e5m2 encode: RNE round two packed f16 to their top bytes.
__device__ inline unsigned rnd8(h2 v) {
    unsigned u = h2u(v);
    return u + 0x007F007Fu + ((u >> 8) & 0x00010001u);
}

// ---------------- CSR build ----------------
__global__ void deg_kernel(const int* __restrict__ dst, int* __restrict__ deg) {
    int e = blockIdx.x * blockDim.x + threadIdx.x;
    if (e < N_EDGES) atomicAdd(&deg[dst[e]], 1);
}

__global__ __launch_bounds__(1024) void scan1_kernel(
        const int* __restrict__ deg, int* __restrict__ row_start,
        int* __restrict__ partials) {
    __shared__ int buf[1024];
    int b = blockIdx.x, t = threadIdx.x;
    int i = b * 1024 + t;
    buf[t] = (i < N_NODES) ? deg[i] : 0;
    __syncthreads();
    for (int off = 1; off < 1024; off <<= 1) {
        int tv = (t >= off) ? buf[t - off] : 0;
        __syncthreads();
        buf[t] += tv;
        __syncthreads();
    }
    if (i < N_NODES) row_start[i + 1] = buf[t];
    if (t == 1023) partials[b] = buf[1023];
}

// per-block offset in-kernel; seeds cursor=row_start; pads col[E..E+16)=0
__global__ __launch_bounds__(1024) void scan3_kernel(
        const int* __restrict__ partials, int* __restrict__ row_start,
        int* __restrict__ cursor, int* __restrict__ col) {
    __shared__ int boff_s;
    int b = blockIdx.x, t = threadIdx.x;
    if (t < 64) {
        int v = (t < b) ? partials[t] : 0;
        #pragma unroll
        for (int off = 32; off >= 1; off >>= 1) v += __shfl_xor(v, off);
        if (t == 0) boff_s = v;
    }
    __syncthreads();
    int boff = boff_s;
    int i = b * 1024 + t;
    if (i < N_NODES) {
        int val = row_start[i + 1] + boff;
        row_start[i + 1] = val;
        if (i + 1 < N_NODES) cursor[i + 1] = val;
    }
    if (i == 0) { row_start[0] = 0; cursor[0] = 0; }
    if (b == 0 && t < 16) col[N_EDGES + t] = 0;   // pad -> no clamps in attn
}

__global__ void fill_kernel(const int* __restrict__ src, const int* __restrict__ dst,
                            int* __restrict__ cursor, int* __restrict__ col) {
    int e = blockIdx.x * blockDim.x + threadIdx.x;
    if (e < N_EDGES) {
        int pos = atomicAdd(&cursor[dst[e]], 1);
        col[pos] = src[e];
    }
}

// ---------------- W fp32 -> fp16 fragment order (8 matrices) ----------------
__global__ __launch_bounds__(256) void convertw_kernel(
        const float* __restrict__ Wq, const float* __restrict__ Wk,
        const float* __restrict__ Wv, const float* __restrict__ Ws,
        unsigned short* __restrict__ wfrag) {
    int b = blockIdx.x;
    int l = b >> 2, m = b & 3;
    const float* W = (m == 0 ? Wq : m == 1 ? Wk : m == 2 ? Wv : Ws) + l * DIM * DIM;
    unsigned short* out = wfrag + (size_t)b * (CHUNKS_PER_TILE * 8);
    for (int i = threadIdx.x; i < CHUNKS_PER_TILE; i += 256) {
        int tile = i >> 6, lane = i & 63;
        int row = (tile >> 2) * 16 + (lane & 15);
        int k0 = (tile & 3) * 32 + (lane >> 4) * 8;
        const float4* p = (const float4*)(W + row * DIM + k0);
        float4 a = p[0], bb = p[1];
        uint4 o;
        o.x = h2u(pkh(a.x, a.y));  o.y = h2u(pkh(a.z, a.w));
        o.z = h2u(pkh(bb.x, bb.y)); o.w = h2u(pkh(bb.z, bb.w));
        *(uint4*)(out + (size_t)i * 8) = o;
    }
}

// ---------------- MFMA linear: Q,V,S fp16 rows; K -> e5m2 128 B rows ----------
template <bool F32IN>
__global__ __launch_bounds__(512) void linear_kernel(
        const void* __restrict__ hb_,
        const unsigned short* __restrict__ wfrag,
        const float* __restrict__ bq, const float* __restrict__ bk,
        const float* __restrict__ bv, const float* __restrict__ bs,
        unsigned short* __restrict__ Qb, uchar* __restrict__ K8,
        unsigned short* __restrict__ V16, unsigned short* __restrict__ Sb) {
    __shared__ unsigned short hs[16384];
    __shared__ unsigned short wsm[16384];
    int tid = threadIdx.x;
    int tile = blockIdx.x;
    uint4* lh = (uint4*)hs;
    uint4* lw = (uint4*)wsm;
    #pragma unroll
    for (int j = 0; j < 4; ++j) {
        int i = tid + j * 512;
        int s = i >> 6, lane = i & 63;
        int row = tile * 128 + ((s >> 2) << 4) + (lane & 15);
        int k0 = ((s & 3) << 5) + ((lane >> 4) << 3);
        row = row < N_NODES ? row : N_NODES - 1;
        if (F32IN) {
            const float* hf = (const float*)hb_;
            const float4* p = (const float4*)(hf + (size_t)row * DIM + k0);
            float4 a = p[0], bb = p[1];
            uint4 o;
            o.x = h2u(pkh(a.x, a.y));  o.y = h2u(pkh(a.z, a.w));
            o.z = h2u(pkh(bb.x, bb.y)); o.w = h2u(pkh(bb.z, bb.w));
            lh[i] = o;
        } else {
            const unsigned short* hh = (const unsigned short*)hb_;
            lh[i] = *(const uint4*)(hh + (size_t)row * DIM + k0);
        }
    }
    int wave = tid >> 6, lane = tid & 63;
    int node = tile * 128 + wave * 16 + (lane & 15);
    int cq = (lane >> 4) * 4;

    #pragma unroll
    for (int m = 0; m < 4; ++m) {
        const uint4* gw = (const uint4*)(wfrag + (size_t)m * (CHUNKS_PER_TILE * 8));
        __syncthreads();
        #pragma unroll
        for (int j = 0; j < 4; ++j) lw[tid + j * 512] = gw[tid + j * 512];
        __syncthreads();

        f32x4 acc[8];
        #pragma unroll
        for (int nt = 0; nt < 8; ++nt) acc[nt] = (f32x4){0.f, 0.f, 0.f, 0.f};
        #pragma unroll
        for (int ks = 0; ks < 4; ++ks) {
            half8 hbv = *(const half8*)(lh + (wave * 4 + ks) * 64 + lane);
            #pragma unroll
            for (int nt = 0; nt < 8; ++nt)
                acc[nt] = __builtin_amdgcn_mfma_f32_16x16x32_f16(
                              *(const half8*)(lw + (nt * 4 + ks) * 64 + lane),
                              hbv, acc[nt], 0, 0, 0);
        }

        const float* bias = (m == 0 ? bq : m == 1 ? bk : m == 2 ? bv : bs);
        if (node < N_NODES) {
            if (m != 1) {
                unsigned short* ob = (m == 0 ? Qb : m == 2 ? V16 : Sb);
                #pragma unroll
                for (int nt = 0; nt < 8; ++nt) {
                    int colv = nt * 16 + cq;
                    float4 bi = *(const float4*)(bias + colv);
                    uint2 o;
                    o.x = h2u(pkh(acc[nt][0] + bi.x, acc[nt][1] + bi.y));
                    o.y = h2u(pkh(acc[nt][2] + bi.z, acc[nt][3] + bi.w));
                    *(uint2*)(ob + (size_t)node * DIM + colv) = o;
                }
            } else {
                uchar* ob = K8 + (size_t)node * DIM;
                #pragma unroll
                for (int nt = 0; nt < 8; ++nt) {
                    int colv = nt * 16 + cq;
                    float4 bi = *(const float4*)(bias + colv);
                    unsigned uA = rnd8(pkh(acc[nt][0] + bi.x, acc[nt][1] + bi.y));
                    unsigned uB = rnd8(pkh(acc[nt][2] + bi.z, acc[nt][3] + bi.w));
                    *(unsigned*)(ob + colv) =
                        __builtin_amdgcn_perm(uB, uA, 0x07050301u);
                }
            }
        }
    }
}

// ---------------- Fused attention + skip + ReLU (+ optional FC/log_softmax) ----
// One wave per dst node; 4 groups of 16 lanes; 16-edge batches with depth-1
// register pipeline. K e5m2 (128 B rows, perm-decode feeds dot2); V fp16
// (decode-free pk_fma). No online max (|p| ~ O(1); exp2 direct in f32).
template <bool LOGITS>
__global__ __launch_bounds__(256) void attn_kernel(
        const unsigned short* __restrict__ Qb, const uchar* __restrict__ K8,
        const unsigned short* __restrict__ V16, const unsigned short* __restrict__ Sb,
        const int* __restrict__ row_start, const int* __restrict__ col,
        unsigned short* __restrict__ hout, float* __restrict__ outF,
        const float* __restrict__ fcW, const float* __restrict__ fcb) {
    int wave = threadIdx.x >> 6;
    int lane = threadIdx.x & 63;
    int g = lane >> 4, gl = lane & 15;
    int n = blockIdx.x * 4 + wave;
    if (n >= N_NODES) return;

    const uchar* Kc = K8 + (gl << 3);                 // 8 B K slice (8 dims, e5m2)
    const uchar* Vc = (const uchar*)V16 + (gl << 4);  // 16 B V slice (8 dims, fp16)
    const float qsf = 0.08838834764831843f * 1.4426950408889634f; // 1/sqrt(128)*log2e
    h2 qsv = pkh(qsf, qsf);
    uint4 qu = *(const uint4*)((const uchar*)Qb + (((unsigned)n) << 8) + (gl << 4));
    h2 q0 = u2h(qu.x) * qsv, q1 = u2h(qu.y) * qsv;
    h2 q2 = u2h(qu.z) * qsv, q3 = u2h(qu.w) * qsv;

    int e0 = row_start[n], e1 = row_start[n + 1];
    int deg = e1 - e0;
    const float NEG = -1.0e30f;
    float den = 0.f;
    h2 a0 = (h2)0, a1 = (h2)0, a2 = (h2)0, a3 = (h2)0;

#define LOAD4(eb_, k_, v_)                                                  \
    do {                                                                     \
        unsigned c0 = (unsigned)col[(eb_)];                                  \
        unsigned c1 = (unsigned)col[(eb_) + 4];                              \
        unsigned c2 = (unsigned)col[(eb_) + 8];                              \
        unsigned c3 = (unsigned)col[(eb_) + 12];                             \
        k_[0] = *(const uint2*)(Kc + (c0 << 7));                             \
        k_[1] = *(const uint2*)(Kc + (c1 << 7));                             \
        k_[2] = *(const uint2*)(Kc + (c2 << 7));                             \
        k_[3] = *(const uint2*)(Kc + (c3 << 7));                             \
        v_[0] = *(const uint4*)(Vc + (c0 << 8));                             \
        v_[1] = *(const uint4*)(Vc + (c1 << 8));                             \
        v_[2] = *(const uint4*)(Vc + (c2 << 8));                             \
        v_[3] = *(const uint4*)(Vc + (c3 << 8));                             \
    } while (0)

#define EDOT(ku_) ({                                                         \
        float p_ = dot2acc(dec2lo((ku_).x), q0, 0.f);                        \
        p_ = dot2acc(dec2hi((ku_).x), q1, p_);                               \
        p_ = dot2acc(dec2lo((ku_).y), q2, p_);                               \
        p_ = dot2acc(dec2hi((ku_).y), q3, p_);                               \
        p_ += __shfl_xor(p_, 1); p_ += __shfl_xor(p_, 2);                    \
        p_ += __shfl_xor(p_, 4); p_ += __shfl_xor(p_, 8);                    \
        p_; })

#define ACCE(w_, vu_)                                                        \
    do {                                                                     \
        h2 w2 = pkh(w_, w_);                                                 \
        a0 = a0 + w2 * u2h((vu_).x);                                         \
        a1 = a1 + w2 * u2h((vu_).y);                                         \
        a2 = a2 + w2 * u2h((vu_).z);                                         \
        a3 = a3 + w2 * u2h((vu_).w);                                         \
    } while (0)

#define COMPUTE4(eb_, k_, v_)                                                \
    do {                                                                     \
        float p0 = EDOT(k_[0]), p1 = EDOT(k_[1]);                            \
        float p2 = EDOT(k_[2]), p3 = EDOT(k_[3]);                            \
        p0 = (eb_) < e1      ? p0 : NEG;                                     \
        p1 = (eb_) + 4 < e1  ? p1 : NEG;                                     \
        p2 = (eb_) + 8 < e1  ? p2 : NEG;                                     \
        p3 = (eb_) + 12 < e1 ? p3 : NEG;                                     \
        float w0 = exp2f(p0), w1 = exp2f(p1);                                \
        float w2_ = exp2f(p2), w3 = exp2f(p3);                               \
        den += (w0 + w1) + (w2_ + w3);                                       \
        ACCE(w0, v_[0]); ACCE(w1, v_[1]);                                    \
        ACCE(w2_, v_[2]); ACCE(w3, v_[3]);                                   \
    } while (0)

    if (deg > 0) {
        int B = (deg + 15) >> 4;                  // wave-uniform
        int eb = e0 + g;
        uint2 k[4]; uint4 v[4];
        LOAD4(eb, k, v);
        for (int b = 0;;) {
            uint2 nk[4]; uint4 nv[4];
            bool more = (b + 1 < B);
            if (more) LOAD4(eb + 16, nk, nv);
            COMPUTE4(eb, k, v);
            if (!more) break;
            ++b; eb += 16;
            #pragma unroll
            for (int i = 0; i < 4; ++i) { k[i] = nk[i]; v[i] = nv[i]; }
        }
    }
#undef LOAD4
#undef EDOT
#undef ACCE
#undef COMPUTE4

    // merge the 4 groups: plain sums (no max/rescale needed)
    float d = den;
    d += __shfl_xor(d, 16);
    d += __shfl_xor(d, 32);
    a0 = a0 + u2h((unsigned)__shfl_xor((int)h2u(a0), 16));
    a0 = a0 + u2h((unsigned)__shfl_xor((int)h2u(a0), 32));
    a1 = a1 + u2h((unsigned)__shfl_xor((int)h2u(a1), 16));
    a1 = a1 + u2h((unsigned)__shfl_xor((int)h2u(a1), 32));
    a2 = a2 + u2h((unsigned)__shfl_xor((int)h2u(a2), 16));
    a2 = a2 + u2h((unsigned)__shfl_xor((int)h2u(a2), 32));
    a3 = a3 + u2h((unsigned)__shfl_xor((int)h2u(a3), 16));
    a3 = a3 + u2h((unsigned)__shfl_xor((int)h2u(a3), 32));
    float inv = (d > 0.f) ? 1.f / d : 0.f;

    uint4 su = *(const uint4*)((const uchar*)Sb + (((unsigned)n) << 8) + (gl << 4));
    h2 s0 = u2h(su.x), s1 = u2h(su.y), s2 = u2h(su.z), s3 = u2h(su.w);
    float o0 = fmaxf(fmaf((float)a0.x, inv, (float)s0.x), 0.f);
    float o1 = fmaxf(fmaf((float)a0.y, inv, (float)s0.y), 0.f);
    float o2 = fmaxf(fmaf((float)a1.x, inv, (float)s1.x), 0.f);
    float o3 = fmaxf(fmaf((float)a1.y, inv, (float)s1.y), 0.f);
    float o4 = fmaxf(fmaf((float)a2.x, inv, (float)s2.x), 0.f);
    float o5 = fmaxf(fmaf((float)a2.y, inv, (float)s2.y), 0.f);
    float o6 = fmaxf(fmaf((float)a3.x, inv, (float)s3.x), 0.f);
    float o7 = fmaxf(fmaf((float)a3.y, inv, (float)s3.y), 0.f);

    if (!LOGITS) {
        if (g == 0) {
            uint4 o;
            o.x = h2u(pkh(o0, o1)); o.y = h2u(pkh(o2, o3));
            o.z = h2u(pkh(o4, o5)); o.w = h2u(pkh(o6, o7));
            *(uint4*)((uchar*)hout + (((unsigned)n) << 8) + (gl << 4)) = o;
        }
    } else {
        float lg[NCLS];
        #pragma unroll
        for (int c = 0; c < NCLS; ++c) {
            const float4* fw = (const float4*)(fcW + c * DIM + gl * 8);
            float4 wa = fw[0], wb = fw[1];
            float pc = o0 * wa.x + o1 * wa.y + o2 * wa.z + o3 * wa.w
                     + o4 * wb.x + o5 * wb.y + o6 * wb.z + o7 * wb.w;
            pc += __shfl_xor(pc, 1); pc += __shfl_xor(pc, 2);
            pc += __shfl_xor(pc, 4); pc += __shfl_xor(pc, 8);
            lg[c] = pc + fcb[c];
        }
        float mx = lg[0];
        #pragma unroll
        for (int c = 1; c < NCLS; ++c) mx = fmaxf(mx, lg[c]);
        float se = 0.f;
        #pragma unroll
        for (int c = 0; c < NCLS; ++c) se += __expf(lg[c] - mx);
        float lse = mx + logf(se);
        if (g == 0 && gl < NCLS) {
            float myv = 0.f;
            #pragma unroll
            for (int c = 0; c < NCLS; ++c) if (gl == c) myv = lg[c];
            outF[(size_t)n * NCLS + gl] = myv - lse;
        }
    }
}

extern "C" void kernel_launch(void* const* d_in, const int* in_sizes, int n_in,
                              void* d_out, int out_size, void* d_ws, size_t ws_size,
                              hipStream_t stream) {
    const float* x   = (const float*)d_in[0];
    const int*   ei  = (const int*)d_in[1];
    const float* Wq  = (const float*)d_in[2];
    const float* bq  = (const float*)d_in[3];
    const float* Wk  = (const float*)d_in[4];
    const float* bk  = (const float*)d_in[5];
    const float* Wv  = (const float*)d_in[6];
    const float* bv  = (const float*)d_in[7];
    const float* Ws  = (const float*)d_in[8];
    const float* bs  = (const float*)d_in[9];
    const float* fcW = (const float*)d_in[10];
    const float* fcb = (const float*)d_in[11];
    const int* src = ei;                 // edge_index[0]
    const int* dst = ei + N_EDGES;       // edge_index[1]

    size_t NF = (size_t)N_NODES * DIM;
    unsigned short* Qb = (unsigned short*)d_ws;             // fp16 [N][128]
    unsigned short* Sb = Qb + NF;                           // fp16 [N][128]
    unsigned short* V16 = Sb + NF;                          // fp16 [N][128]
    uchar* K8 = (uchar*)(V16 + NF);                         // e5m2 [N][128]
    unsigned short* h1 = (unsigned short*)(K8 + NF);        // fp16 [N][128]
    unsigned short* wfrag = h1 + NF;                        // 8 * 2048 * 8 fp16
    int* ints      = (int*)(wfrag + 8 * CHUNKS_PER_TILE * 8);
    int* row_start = ints;                       // N+1
    int* cursor    = row_start + N_NODES + 1;    // N
    int* col       = cursor + N_NODES;           // E + 16 pad
    int* partials  = col + N_EDGES + 16;         // NB_SCAN

    // CSR by destination
    (void)hipMemsetAsync(cursor, 0, N_NODES * sizeof(int), stream);
    deg_kernel<<<(N_EDGES + 255) / 256, 256, 0, stream>>>(dst, cursor);
    scan1_kernel<<<NB_SCAN, 1024, 0, stream>>>(cursor, row_start, partials);
    scan3_kernel<<<NB_SCAN, 1024, 0, stream>>>(partials, row_start, cursor, col);
    fill_kernel<<<(N_EDGES + 255) / 256, 256, 0, stream>>>(src, dst, cursor, col);

    convertw_kernel<<<8, 256, 0, stream>>>(Wq, Wk, Wv, Ws, wfrag);

    const int AGRID = (N_NODES + 3) / 4;

    // layer 1 (reads fp32 x directly)
    linear_kernel<true><<<MTILES, 512, 0, stream>>>(x, wfrag, bq, bk, bv, bs,
                                                    Qb, K8, V16, Sb);
    attn_kernel<false><<<AGRID, 256, 0, stream>>>(Qb, K8, V16, Sb, row_start, col,
                                                  h1, nullptr, nullptr, nullptr);
    // layer 2 + fused FC/log_softmax
    linear_kernel<false><<<MTILES, 512, 0, stream>>>(h1, wfrag + 4 * CHUNKS_PER_TILE * 8,
                                                     bq + DIM, bk + DIM, bv + DIM, bs + DIM,
                                                     Qb, K8, V16, Sb);
    attn_kernel<true><<<AGRID, 256, 0, stream>>>(Qb, K8, V16, Sb, row_start, col,
                                                 nullptr, (float*)d_out, fcW, fcb);
}

// Round 19
// 226.152 us; speedup vs baseline: 1.0460x; 1.0460x over previous
//
#include <hip/hip_runtime.h>
#include <math.h>

#define N_NODES 50000
#define N_EDGES 600000
#define DIM 128
#define NCLS 10
#define MTILES 391                       // ceil(50000/128)
#define CHUNKS_PER_TILE 2048             // 32 slots * 64 lanes, 8 fp16 each
#define NB_SCAN 49                       // ceil(50000/1024)

typedef _Float16 h2 __attribute__((ext_vector_type(2)));
typedef _Float16 half8 __attribute__((ext_vector_type(8)));
typedef __attribute__((ext_vector_type(4))) float f32x4;
typedef unsigned char uchar;

__device__ inline h2 pkh(float a, float b) {        // 2xf32 -> packed fp16 (RTZ)
    auto r = __builtin_amdgcn_cvt_pkrtz(a, b);
    return *(h2*)&r;
}
__device__ inline unsigned h2u(h2 v) { return *(unsigned*)&v; }
__device__ inline h2 u2h(unsigned u) { return *(h2*)&u; }

__device__ inline float dot2acc(h2 a, h2 b, float c) {
#if __has_builtin(__builtin_amdgcn_fdot2)
    return __builtin_amdgcn_fdot2(a, b, c, false);   // v_dot2_f32_f16
#else
    return fmaf((float)a.x, (float)b.x, fmaf((float)a.y, (float)b.y, c));
#endif
}

// e5m2 decode: byte is the TOP byte of an f16; one v_perm_b32 per h2 pair.
__device__ inline h2 dec2lo(unsigned w) {   // bytes 0,1 -> h2
    return u2h(__builtin_amdgcn_perm(0u, w, 0x010C000Cu));
}
__device__ inline h2 dec2hi(unsigned w) {   // bytes 2,3 -> h2
    return u2h(__builtin_amdgcn_perm(0u, w, 0x030C020Cu));
}
// e5m2 encode: RNE round two packed f16 to their top bytes.
__device__ inline unsigned rnd8(h2 v) {
    unsigned u = h2u(v);
    return u + 0x007F007Fu + ((u >> 8) & 0x00010001u);
}

// ---------------- CSR build ----------------
__global__ void deg_kernel(const int* __restrict__ dst, int* __restrict__ deg) {
    int e = blockIdx.x * blockDim.x + threadIdx.x;
    if (e < N_EDGES) atomicAdd(&deg[dst[e]], 1);
}

__global__ __launch_bounds__(1024) void scan1_kernel(
        const int* __restrict__ deg, int* __restrict__ row_start,
        int* __restrict__ partials) {
    __shared__ int buf[1024];
    int b = blockIdx.x, t = threadIdx.x;
    int i = b * 1024 + t;
    buf[t] = (i < N_NODES) ? deg[i] : 0;
    __syncthreads();
    for (int off = 1; off < 1024; off <<= 1) {
        int tv = (t >= off) ? buf[t - off] : 0;
        __syncthreads();
        buf[t] += tv;
        __syncthreads();
    }
    if (i < N_NODES) row_start[i + 1] = buf[t];
    if (t == 1023) partials[b] = buf[1023];
}

// per-block offset in-kernel; seeds cursor=row_start; pads col[E..E+16)=0
__global__ __launch_bounds__(1024) void scan3_kernel(
        const int* __restrict__ partials, int* __restrict__ row_start,
        int* __restrict__ cursor, int* __restrict__ col) {
    __shared__ int boff_s;
    int b = blockIdx.x, t = threadIdx.x;
    if (t < 64) {
        int v = (t < b) ? partials[t] : 0;
        #pragma unroll
        for (int off = 32; off >= 1; off >>= 1) v += __shfl_xor(v, off);
        if (t == 0) boff_s = v;
    }
    __syncthreads();
    int boff = boff_s;
    int i = b * 1024 + t;
    if (i < N_NODES) {
        int val = row_start[i + 1] + boff;
        row_start[i + 1] = val;
        if (i + 1 < N_NODES) cursor[i + 1] = val;
    }
    if (i == 0) { row_start[0] = 0; cursor[0] = 0; }
    if (b == 0 && t < 16) col[N_EDGES + t] = 0;   // pad -> no clamps in attn
}

__global__ void fill_kernel(const int* __restrict__ src, const int* __restrict__ dst,
                            int* __restrict__ cursor, int* __restrict__ col) {
    int e = blockIdx.x * blockDim.x + threadIdx.x;
    if (e < N_EDGES) {
        int pos = atomicAdd(&cursor[dst[e]], 1);
        col[pos] = src[e];
    }
}

// ---------------- W fp32 -> fp16 fragment order (8 matrices) ----------------
__global__ __launch_bounds__(256) void convertw_kernel(
        const float* __restrict__ Wq, const float* __restrict__ Wk,
        const float* __restrict__ Wv, const float* __restrict__ Ws,
        unsigned short* __restrict__ wfrag) {
    int b = blockIdx.x;
    int l = b >> 2, m = b & 3;
    const float* W = (m == 0 ? Wq : m == 1 ? Wk : m == 2 ? Wv : Ws) + l * DIM * DIM;
    unsigned short* out = wfrag + (size_t)b * (CHUNKS_PER_TILE * 8);
    for (int i = threadIdx.x; i < CHUNKS_PER_TILE; i += 256) {
        int tile = i >> 6, lane = i & 63;
        int row = (tile >> 2) * 16 + (lane & 15);
        int k0 = (tile & 3) * 32 + (lane >> 4) * 8;
        const float4* p = (const float4*)(W + row * DIM + k0);
        float4 a = p[0], bb = p[1];
        uint4 o;
        o.x = h2u(pkh(a.x, a.y));  o.y = h2u(pkh(a.z, a.w));
        o.z = h2u(pkh(bb.x, bb.y)); o.w = h2u(pkh(bb.z, bb.w));
        *(uint4*)(out + (size_t)i * 8) = o;
    }
}

// ---------------- MFMA linear: Q,S fp16 rows; K,V -> e5m2 128 B rows ----------
template <bool F32IN>
__global__ __launch_bounds__(512) void linear_kernel(
        const void* __restrict__ hb_,
        const unsigned short* __restrict__ wfrag,
        const float* __restrict__ bq, const float* __restrict__ bk,
        const float* __restrict__ bv, const float* __restrict__ bs,
        unsigned short* __restrict__ Qb, uchar* __restrict__ K8,
        uchar* __restrict__ V8, unsigned short* __restrict__ Sb) {
    __shared__ unsigned short hs[16384];
    __shared__ unsigned short wsm[16384];
    int tid = threadIdx.x;
    int tile = blockIdx.x;
    uint4* lh = (uint4*)hs;
    uint4* lw = (uint4*)wsm;
    #pragma unroll
    for (int j = 0; j < 4; ++j) {
        int i = tid + j * 512;
        int s = i >> 6, lane = i & 63;
        int row = tile * 128 + ((s >> 2) << 4) + (lane & 15);
        int k0 = ((s & 3) << 5) + ((lane >> 4) << 3);
        row = row < N_NODES ? row : N_NODES - 1;
        if (F32IN) {
            const float* hf = (const float*)hb_;
            const float4* p = (const float4*)(hf + (size_t)row * DIM + k0);
            float4 a = p[0], bb = p[1];
            uint4 o;
            o.x = h2u(pkh(a.x, a.y));  o.y = h2u(pkh(a.z, a.w));
            o.z = h2u(pkh(bb.x, bb.y)); o.w = h2u(pkh(bb.z, bb.w));
            lh[i] = o;
        } else {
            const unsigned short* hh = (const unsigned short*)hb_;
            lh[i] = *(const uint4*)(hh + (size_t)row * DIM + k0);
        }
    }
    int wave = tid >> 6, lane = tid & 63;
    int node = tile * 128 + wave * 16 + (lane & 15);
    int cq = (lane >> 4) * 4;

    #pragma unroll
    for (int m = 0; m < 4; ++m) {
        const uint4* gw = (const uint4*)(wfrag + (size_t)m * (CHUNKS_PER_TILE * 8));
        __syncthreads();
        #pragma unroll
        for (int j = 0; j < 4; ++j) lw[tid + j * 512] = gw[tid + j * 512];
        __syncthreads();

        f32x4 acc[8];
        #pragma unroll
        for (int nt = 0; nt < 8; ++nt) acc[nt] = (f32x4){0.f, 0.f, 0.f, 0.f};
        #pragma unroll
        for (int ks = 0; ks < 4; ++ks) {
            half8 hbv = *(const half8*)(lh + (wave * 4 + ks) * 64 + lane);
            #pragma unroll
            for (int nt = 0; nt < 8; ++nt)
                acc[nt] = __builtin_amdgcn_mfma_f32_16x16x32_f16(
                              *(const half8*)(lw + (nt * 4 + ks) * 64 + lane),
                              hbv, acc[nt], 0, 0, 0);
        }

        const float* bias = (m == 0 ? bq : m == 1 ? bk : m == 2 ? bv : bs);
        if (node < N_NODES) {
            if (m == 0 || m == 3) {
                unsigned short* ob = (m == 0) ? Qb : Sb;
                #pragma unroll
                for (int nt = 0; nt < 8; ++nt) {
                    int colv = nt * 16 + cq;
                    float4 bi = *(const float4*)(bias + colv);
                    uint2 o;
                    o.x = h2u(pkh(acc[nt][0] + bi.x, acc[nt][1] + bi.y));
                    o.y = h2u(pkh(acc[nt][2] + bi.z, acc[nt][3] + bi.w));
                    *(uint2*)(ob + (size_t)node * DIM + colv) = o;
                }
            } else {
                uchar* ob = ((m == 1) ? K8 : V8) + (size_t)node * DIM;
                #pragma unroll
                for (int nt = 0; nt < 8; ++nt) {
                    int colv = nt * 16 + cq;
                    float4 bi = *(const float4*)(bias + colv);
                    unsigned uA = rnd8(pkh(acc[nt][0] + bi.x, acc[nt][1] + bi.y));
                    unsigned uB = rnd8(pkh(acc[nt][2] + bi.z, acc[nt][3] + bi.w));
                    *(unsigned*)(ob + colv) =
                        __builtin_amdgcn_perm(uB, uA, 0x07050301u);
                }
            }
        }
    }
}

// ---------------- Fused attention + skip + ReLU (+ optional FC/log_softmax) ----
// One wave per dst node; 4 groups of 16 lanes; 16-edge batches. e5m2 K/V
// (128 B rows), perm-decode to fp16, dot2 for scores, pk_fma accumulate.
// NO online max: scores are O(1) (|p| << 100), exp2 direct in f32 is safe;
// removes the max tree, acc rescale, and all serial softmax chains.
template <bool LOGITS>
__global__ __launch_bounds__(256, 4) void attn_kernel(
        const unsigned short* __restrict__ Qb, const uchar* __restrict__ K8,
        const uchar* __restrict__ V8, const unsigned short* __restrict__ Sb,
        const int* __restrict__ row_start, const int* __restrict__ col,
        unsigned short* __restrict__ hout, float* __restrict__ outF,
        const float* __restrict__ fcW, const float* __restrict__ fcb) {
    int wave = threadIdx.x >> 6;
    int lane = threadIdx.x & 63;
    int g = lane >> 4, gl = lane & 15;
    int n = blockIdx.x * 4 + wave;
    if (n >= N_NODES) return;

    const uchar* Kc = K8 + (gl << 3);        // 8 B slice per lane (8 dims)
    const uchar* Vc = V8 + (gl << 3);
    const float qsf = 0.08838834764831843f * 1.4426950408889634f; // 1/sqrt(128)*log2e
    h2 qsv = pkh(qsf, qsf);
    uint4 qu = *(const uint4*)((const uchar*)Qb + (((unsigned)n) << 8) + (gl << 4));
    h2 q0 = u2h(qu.x) * qsv, q1 = u2h(qu.y) * qsv;
    h2 q2 = u2h(qu.z) * qsv, q3 = u2h(qu.w) * qsv;

    int e0 = row_start[n], e1 = row_start[n + 1];
    int deg = e1 - e0;
    const float NEG = -1.0e30f;
    float den = 0.f;
    h2 a0 = (h2)0, a1 = (h2)0, a2 = (h2)0, a3 = (h2)0;

#define LOAD4(eb_, k_, v_)                                                  \
    do {                                                                     \
        unsigned o0 = ((unsigned)col[(eb_)]) << 7;                           \
        unsigned o1 = ((unsigned)col[(eb_) + 4]) << 7;                       \
        unsigned o2 = ((unsigned)col[(eb_) + 8]) << 7;                       \
        unsigned o3 = ((unsigned)col[(eb_) + 12]) << 7;                      \
        k_[0] = *(const uint2*)(Kc + o0); v_[0] = *(const uint2*)(Vc + o0);  \
        k_[1] = *(const uint2*)(Kc + o1); v_[1] = *(const uint2*)(Vc + o1);  \
        k_[2] = *(const uint2*)(Kc + o2); v_[2] = *(const uint2*)(Vc + o2);  \
        k_[3] = *(const uint2*)(Kc + o3); v_[3] = *(const uint2*)(Vc + o3);  \
    } while (0)

#define EDOT(ku_) ({                                                         \
        float p_ = dot2acc(dec2lo((ku_).x), q0, 0.f);                        \
        p_ = dot2acc(dec2hi((ku_).x), q1, p_);                               \
        p_ = dot2acc(dec2lo((ku_).y), q2, p_);                               \
        p_ = dot2acc(dec2hi((ku_).y), q3, p_);                               \
        p_ += __shfl_xor(p_, 1); p_ += __shfl_xor(p_, 2);                    \
        p_ += __shfl_xor(p_, 4); p_ += __shfl_xor(p_, 8);                    \
        p_; })

#define ACCE(w_, vu_)                                                        \
    do {                                                                     \
        h2 w2 = pkh(w_, w_);                                                 \
        a0 = a0 + w2 * dec2lo((vu_).x);                                      \
        a1 = a1 + w2 * dec2hi((vu_).x);                                      \
        a2 = a2 + w2 * dec2lo((vu_).y);                                      \
        a3 = a3 + w2 * dec2hi((vu_).y);                                      \
    } while (0)

#define COMPUTE4(eb_, k_, v_)                                                \
    do {                                                                     \
        float p0 = EDOT(k_[0]), p1 = EDOT(k_[1]);                            \
        float p2 = EDOT(k_[2]), p3 = EDOT(k_[3]);                            \
        p0 = (eb_) < e1      ? p0 : NEG;                                     \
        p1 = (eb_) + 4 < e1  ? p1 : NEG;                                     \
        p2 = (eb_) + 8 < e1  ? p2 : NEG;                                     \
        p3 = (eb_) + 12 < e1 ? p3 : NEG;                                     \
        float w0 = exp2f(p0), w1 = exp2f(p1);                                \
        float w2_ = exp2f(p2), w3 = exp2f(p3);                               \
        den += (w0 + w1) + (w2_ + w3);                                       \
        ACCE(w0, v_[0]); ACCE(w1, v_[1]);                                    \
        ACCE(w2_, v_[2]); ACCE(w3, v_[3]);                                   \
    } while (0)

    if (deg > 0) {
        int B = (deg + 15) >> 4;                  // wave-uniform
        int eb = e0 + g;
        uint2 k[4], v[4];
        LOAD4(eb, k, v);
        for (int b = 0;;) {
            uint2 nk[4], nv[4];
            bool more = (b + 1 < B);
            if (more) LOAD4(eb + 16, nk, nv);
            COMPUTE4(eb, k, v);
            if (!more) break;
            ++b; eb += 16;
            #pragma unroll
            for (int i = 0; i < 4; ++i) { k[i] = nk[i]; v[i] = nv[i]; }
        }
    }
#undef LOAD4
#undef EDOT
#undef ACCE
#undef COMPUTE4

    // merge the 4 groups: plain sums (no max/rescale needed)
    float d = den;
    d += __shfl_xor(d, 16);
    d += __shfl_xor(d, 32);
    a0 = a0 + u2h((unsigned)__shfl_xor((int)h2u(a0), 16));
    a0 = a0 + u2h((unsigned)__shfl_xor((int)h2u(a0), 32));
    a1 = a1 + u2h((unsigned)__shfl_xor((int)h2u(a1), 16));
    a1 = a1 + u2h((unsigned)__shfl_xor((int)h2u(a1), 32));
    a2 = a2 + u2h((unsigned)__shfl_xor((int)h2u(a2), 16));
    a2 = a2 + u2h((unsigned)__shfl_xor((int)h2u(a2), 32));
    a3 = a3 + u2h((unsigned)__shfl_xor((int)h2u(a3), 16));
    a3 = a3 + u2h((unsigned)__shfl_xor((int)h2u(a3), 32));
    float inv = (d > 0.f) ? 1.f / d : 0.f;

    uint4 su = *(const uint4*)((const uchar*)Sb + (((unsigned)n) << 8) + (gl << 4));
    h2 s0 = u2h(su.x), s1 = u2h(su.y), s2 = u2h(su.z), s3 = u2h(su.w);
    float o0 = fmaxf(fmaf((float)a0.x, inv, (float)s0.x), 0.f);
    float o1 = fmaxf(fmaf((float)a0.y, inv, (float)s0.y), 0.f);
    float o2 = fmaxf(fmaf((float)a1.x, inv, (float)s1.x), 0.f);
    float o3 = fmaxf(fmaf((float)a1.y, inv, (float)s1.y), 0.f);
    float o4 = fmaxf(fmaf((float)a2.x, inv, (float)s2.x), 0.f);
    float o5 = fmaxf(fmaf((float)a2.y, inv, (float)s2.y), 0.f);
    float o6 = fmaxf(fmaf((float)a3.x, inv, (float)s3.x), 0.f);
    float o7 = fmaxf(fmaf((float)a3.y, inv, (float)s3.y), 0.f);

    if (!LOGITS) {
        if (g == 0) {
            uint4 o;
            o.x = h2u(pkh(o0, o1)); o.y = h2u(pkh(o2, o3));
            o.z = h2u(pkh(o4, o5)); o.w = h2u(pkh(o6, o7));
            *(uint4*)((uchar*)hout + (((unsigned)n) << 8) + (gl << 4)) = o;
        }
    } else {
        float lg[NCLS];
        #pragma unroll
        for (int c = 0; c < NCLS; ++c) {
            const float4* fw = (const float4*)(fcW + c * DIM + gl * 8);
            float4 wa = fw[0], wb = fw[1];
            float pc = o0 * wa.x + o1 * wa.y + o2 * wa.z + o3 * wa.w
                     + o4 * wb.x + o5 * wb.y + o6 * wb.z + o7 * wb.w;
            pc += __shfl_xor(pc, 1); pc += __shfl_xor(pc, 2);
            pc += __shfl_xor(pc, 4); pc += __shfl_xor(pc, 8);
            lg[c] = pc + fcb[c];
        }
        float mx = lg[0];
        #pragma unroll
        for (int c = 1; c < NCLS; ++c) mx = fmaxf(mx, lg[c]);
        float se = 0.f;
        #pragma unroll
        for (int c = 0; c < NCLS; ++c) se += __expf(lg[c] - mx);
        float lse = mx + logf(se);
        if (g == 0 && gl < NCLS) {
            float myv = 0.f;
            #pragma unroll
            for (int c = 0; c < NCLS; ++c) if (gl == c) myv = lg[c];
            outF[(size_t)n * NCLS + gl] = myv - lse;
        }
    }
}

extern "C" void kernel_launch(void* const* d_in, const int* in_sizes, int n_in,
                              void* d_out, int out_size, void* d_ws, size_t ws_size,
                              hipStream_t stream) {
    const float* x   = (const float*)d_in[0];
    const int*   ei  = (const int*)d_in[1];
    const float* Wq  = (const float*)d_in[2];
    const float* bq  = (const float*)d_in[3];
    const float* Wk  = (const float*)d_in[4];
    const float* bk  = (const float*)d_in[5];
    const float* Wv  = (const float*)d_in[6];
    const float* bv  = (const float*)d_in[7];
    const float* Ws  = (const float*)d_in[8];
    const float* bs  = (const float*)d_in[9];
    const float* fcW = (const float*)d_in[10];
    const float* fcb = (const float*)d_in[11];
    const int* src = ei;                 // edge_index[0]
    const int* dst = ei + N_EDGES;       // edge_index[1]

    size_t NF = (size_t)N_NODES * DIM;
    unsigned short* Qb = (unsigned short*)d_ws;             // fp16 [N][128]
    unsigned short* Sb = Qb + NF;                           // fp16 [N][128]
    uchar* K8 = (uchar*)(Sb + NF);                          // e5m2 [N][128]
    uchar* V8 = K8 + NF;                                    // e5m2 [N][128]
    unsigned short* h1 = (unsigned short*)(V8 + NF);        // fp16 [N][128]
    unsigned short* wfrag = h1 + NF;                        // 8 * 2048 * 8 fp16
    int* ints      = (int*)(wfrag + 8 * CHUNKS_PER_TILE * 8);
    int* row_start = ints;                       // N+1
    int* cursor    = row_start + N_NODES + 1;    // N
    int* col       = cursor + N_NODES;           // E + 16 pad
    int* partials  = col + N_EDGES + 16;         // NB_SCAN

    // CSR by destination
    (void)hipMemsetAsync(cursor, 0, N_NODES * sizeof(int), stream);
    deg_kernel<<<(N_EDGES + 255) / 256, 256, 0, stream>>>(dst, cursor);
    scan1_kernel<<<NB_SCAN, 1024, 0, stream>>>(cursor, row_start, partials);
    scan3_kernel<<<NB_SCAN, 1024, 0, stream>>>(partials, row_start, cursor, col);
    fill_kernel<<<(N_EDGES + 255) / 256, 256, 0, stream>>>(src, dst, cursor, col);

    convertw_kernel<<<8, 256, 0, stream>>>(Wq, Wk, Wv, Ws, wfrag);

    const int AGRID = (N_NODES + 3) / 4;

    // layer 1 (reads fp32 x directly)
    linear_kernel<true><<<MTILES, 512, 0, stream>>>(x, wfrag, bq, bk, bv, bs,
                                                    Qb, K8, V8, Sb);
    attn_kernel<false><<<AGRID, 256, 0, stream>>>(Qb, K8, V8, Sb, row_start, col,
                                                  h1, nullptr, nullptr, nullptr);
    // layer 2 + fused FC/log_softmax
    linear_kernel<false><<<MTILES, 512, 0, stream>>>(h1, wfrag + 4 * CHUNKS_PER_TILE * 8,
                                                     bq + DIM, bk + DIM, bv + DIM, bs + DIM,
                                                     Qb, K8, V8, Sb);
    attn_kernel<true><<<AGRID, 256, 0, stream>>>(Qb, K8, V8, Sb, row_start, col,
                                                 nullptr, (float*)d_out, fcW, fcb);
}